// Round 7
// baseline (276.848 us; speedup 1.0000x reference)
//
#include <hip/hip_runtime.h>
#include <hip/hip_fp16.h>
#include <math.h>

// EnvironmentLight IBL shade, R15.
// R14 post-mortem: zero-LDS direct = 84us, VGPR 28, no spill, occupancy ~73%
// (same ~23 waves/CU as R10 despite 32-wave cap). Concurrency arithmetic:
// 32.8K scattered loads/CU x 600cyc / 200K cyc = ~98 in flight = 23 waves x 4.
// => latency-bound, capped by 4 scattered loads PER WAVE. Lever: loads/wave.
// R15: 2 pts/thread on the 28-VGPR direct body (no LDS, no LDS-read bloat
// that spilled R11/R12). prep0 -> prep1 -> finish0 -> finish1, all in regs.
// 8 scattered loads in flight/wave. launch_bounds(256,6) = 84 VGPR cap.
// Diagnostics: WRITE_SIZE must stay 24.6MB; dur unchanged w/o spill would
// instead indicate a shared-resource (L3/TA) ceiling.

typedef unsigned int u32;

// ---------------- RGB9E5 ----------------
__device__ __forceinline__ u32 enc9e5(float r, float g, float b) {
    r = fminf(fmaxf(r, 0.f), 65408.f);
    g = fminf(fmaxf(g, 0.f), 65408.f);
    b = fminf(fmaxf(b, 0.f), 65408.f);
    float maxc = fmaxf(r, fmaxf(g, b));
    int e = ((__float_as_int(maxc) >> 23) & 0xff) - 127;
    int exp_p = max(e + 16, 0);
    float rd = __int_as_float((151 - exp_p) << 23);   // 2^(24-exp_p), exact
    int maxm = (int)(maxc * rd + 0.5f);
    if (maxm == 512) { exp_p += 1; rd *= 0.5f; }
    u32 rm = (u32)(r * rd + 0.5f);
    u32 gm = (u32)(g * rd + 0.5f);
    u32 bm = (u32)(b * rd + 0.5f);
    return rm | (gm << 9) | (bm << 18) | ((u32)exp_p << 27);
}

__device__ __forceinline__ void dec9e5_acc(u32 pk, float w, float& r, float& g, float& b) {
    float scale = __int_as_float((int)(((pk >> 27) & 31u) + 103u) << 23) * w;
    r += (float)(pk & 511u) * scale;
    g += (float)((pk >> 9) & 511u) * scale;
    b += (float)((pk >> 18) & 511u) * scale;
}

__device__ __forceinline__ void gather_q9(uint4 q, float tx, float ty,
                                          float& r, float& g, float& b) {
    float w00 = (1.f - tx) * (1.f - ty);
    float w01 = tx * (1.f - ty);
    float w10 = (1.f - tx) * ty;
    float w11 = tx * ty;
    r = 0.f; g = 0.f; b = 0.f;
    dec9e5_acc(q.x, w00, r, g, b);
    dec9e5_acc(q.y, w01, r, g, b);
    dec9e5_acc(q.z, w10, r, g, b);
    dec9e5_acc(q.w, w11, r, g, b);
}

__device__ __forceinline__ float srgb1(float x) {
    float p = 1.055f * __builtin_amdgcn_exp2f(
                  __builtin_amdgcn_logf(fmaxf(x, 0.0031308f)) * (1.0f / 2.4f)) - 0.055f;
    return (x <= 0.0031308f) ? (12.92f * x) : p;
}

__device__ __forceinline__ void cube_face_uv(float dx, float dy, float dz,
                                             int& face, float& u, float& v) {
    float ax = fabsf(dx), ay = fabsf(dy), az = fabsf(dz);
    bool is_x = (ax >= ay) && (ax >= az);
    bool is_y = (!is_x) && (ay >= az);
    face = is_x ? (dx > 0.f ? 0 : 1)
                : (is_y ? (dy > 0.f ? 2 : 3) : (dz > 0.f ? 4 : 5));
    float ma = fmaxf(is_x ? ax : (is_y ? ay : az), 1e-20f);
    float uu = is_x ? (dx > 0.f ? -dz : dz) : (is_y ? dx : (dz > 0.f ? dx : -dx));
    float vv = is_y ? (dy > 0.f ? dz : -dz) : -dy;
    float inv = __builtin_amdgcn_rcpf(ma);
    u = uu * inv;
    v = vv * inv;
}

// ---------------- layout constants ----------------
#define SPEC_TOTAL 2096640
#define DIF_OFF    SPEC_TOTAL
#define LUT_OFF    (SPEC_TOTAL + 1536)
#define ALL_QUADS  (SPEC_TOTAL + 1536 + 65536)
#define N_TILES    8452   // 8190 spec + 6 dif + 256 lut

// OFF(l) = 2^21 - (2^21 >> 2l): 0,1572864,1966080,2064384,2088960,2095104
__device__ __forceinline__ int spec_off(int l) {
    return (1 << 21) - ((1 << 21) >> (2 * l));
}

// ---------------- tiled repack (unchanged from R11, verified) ----------------
__global__ __launch_bounds__(256)
void repack_tiled(const float* __restrict__ s0, const float* __restrict__ s1,
                  const float* __restrict__ s2, const float* __restrict__ s3,
                  const float* __restrict__ s4, const float* __restrict__ s5,
                  const float* __restrict__ diffuse_map,
                  const float2* __restrict__ lut,
                  uint4* __restrict__ dst)
{
    __shared__ u32 L[289];
    int b = blockIdx.x;
    int tid = threadIdx.x;

    if (b >= 8196) {
        int t = b - 8196;
        int ty0 = (t >> 4) << 4;
        int tx0 = (t & 15) << 4;
        for (int e = tid; e < 289; e += 256) {
            int ey = e / 17, ex = e - ey * 17;
            int gy = min(ty0 + ey, 255), gx = min(tx0 + ex, 255);
            float2 c = lut[(gy << 8) + gx];
            __half2 h = __floats2half2_rn(c.x, c.y);
            L[e] = *reinterpret_cast<u32*>(&h);
        }
        __syncthreads();
        int qx = tid & 15, qy = tid >> 4;
        uint4 qv;
        qv.x = L[qy * 17 + qx];       qv.y = L[qy * 17 + qx + 1];
        qv.z = L[(qy + 1) * 17 + qx]; qv.w = L[(qy + 1) * 17 + qx + 1];
        dst[LUT_OFF + ((ty0 + qy) << 8) + tx0 + qx] = qv;
        return;
    }

    const float* src; int lr, tbase, doff;
    if      (b < 6144) { src = s0; lr = 9; tbase = 0;    doff = 0; }
    else if (b < 7680) { src = s1; lr = 8; tbase = 6144; doff = 1572864; }
    else if (b < 8064) { src = s2; lr = 7; tbase = 7680; doff = 1966080; }
    else if (b < 8160) { src = s3; lr = 6; tbase = 8064; doff = 2064384; }
    else if (b < 8184) { src = s4; lr = 5; tbase = 8160; doff = 2088960; }
    else if (b < 8190) { src = s5; lr = 4; tbase = 8184; doff = 2095104; }
    else               { src = diffuse_map; lr = 4; tbase = 8190; doff = DIF_OFF; }

    int W = 1 << lr;
    int lt = lr - 4;
    int local = b - tbase;
    int face = local >> (2 * lt);
    int rem  = local & ((1 << (2 * lt)) - 1);
    int ty0 = (rem >> lt) << 4;
    int tx0 = (rem & ((1 << lt) - 1)) << 4;
    int fbase = face << (2 * lr);

    for (int e = tid; e < 289; e += 256) {
        int ey = e / 17, ex = e - ey * 17;
        int gy = min(ty0 + ey, W - 1), gx = min(tx0 + ex, W - 1);
        int idx = 3 * (fbase + (gy << lr) + gx);
        L[e] = enc9e5(src[idx], src[idx + 1], src[idx + 2]);
    }
    __syncthreads();
    int qx = tid & 15, qy = tid >> 4;
    uint4 qv;
    qv.x = L[qy * 17 + qx];       qv.y = L[qy * 17 + qx + 1];
    qv.z = L[(qy + 1) * 17 + qx]; qv.w = L[(qy + 1) * 17 + qx + 1];
    dst[doff + fbase + ((ty0 + qy) << lr) + tx0 + qx] = qv;
}

// ---------------- per-point state ----------------
struct PtS {
    float kdx, kdy, kdz, ks0, met, occ;
    float dtx, dty, ltx, lty, atx, aty, btx, bty, fmip;
};

// prep: direct global input loads, address math, ISSUE 4 scattered loads.
__device__ __forceinline__ void prep_d(
    const float* __restrict__ vd, const float* __restrict__ nm,
    const float* __restrict__ kd, const float* __restrict__ ks,
    const float* __restrict__ oc, const uint4* __restrict__ q, int i,
    PtS& p, uint4& qA, uint4& qB, uint4& ql, uint4& qd)
{
    const float3 v3 = ((const float3*)vd)[i];
    const float3 n3 = ((const float3*)nm)[i];
    const float3 k3 = ((const float3*)kd)[i];
    const float3 s3 = ((const float3*)ks)[i];
    p.occ = oc[i];

    p.kdx = k3.x; p.kdy = k3.y; p.kdz = k3.z;
    p.ks0 = s3.x; p.met = s3.z;
    float rough = s3.y;

    float vx = v3.x, vy = v3.y, vz = v3.z;
    float nx = n3.x, ny = n3.y, nz = n3.z;

    // reflect + normalize
    float vdotn = vx * nx + vy * ny + vz * nz;
    float rx = 2.f * vdotn * nx - vx;
    float ry = 2.f * vdotn * ny - vy;
    float rz = 2.f * vdotn * nz - vz;
    float rinv = __builtin_amdgcn_rsqf(fmaxf(rx * rx + ry * ry + rz * rz, 1e-20f));
    rx *= rinv; ry *= rinv; rz *= rinv;

    // diffuse address (lr=4)
    int dI;
    {
        int face; float u, v;
        cube_face_uv(nx, ny, nz, face, u, v);
        float fx = (u * 0.5f + 0.5f) * 16.f - 0.5f;
        float fy = (v * 0.5f + 0.5f) * 16.f - 0.5f;
        float x0f = floorf(fx), y0f = floorf(fy);
        p.dtx = fx - x0f; p.dty = fy - y0f;
        int x0 = min(max((int)x0f, 0), 15);
        int y0 = min(max((int)y0f, 0), 15);
        dI = DIF_OFF + (face << 8) + (y0 << 4) + x0;
    }

    // LUT address
    int lI;
    {
        float NdotV = fmaxf(vdotn, 1e-4f);
        float fx = NdotV * 256.f - 0.5f;
        float fy = rough * 256.f - 0.5f;
        float x0f = floorf(fx), y0f = floorf(fy);
        p.ltx = fx - x0f; p.lty = fy - y0f;
        int x0 = min(max((int)x0f, 0), 255);
        int y0 = min(max((int)y0f, 0), 255);
        lI = LUT_OFF + (y0 << 8) + x0;
    }

    // mip selection
    const float MINR = 0.08f, MAXR = 0.5f;
    float lo = (fminf(fmaxf(rough, MINR), MAXR) - MINR) * (4.0f / (MAXR - MINR));
    float hi = (fminf(fmaxf(rough, MAXR), 1.0f) - MAXR) * (1.0f / (1.0f - MAXR)) + 4.0f;
    float lvl = fminf(fmaxf((rough < MAXR) ? lo : hi, 0.f), 5.f);
    int l0 = min(max((int)floorf(lvl), 0), 5);
    int l1 = min(l0 + 1, 5);
    p.fmip = lvl - (float)l0;

    // spec A/B addresses
    int aI, bI;
    {
        int face; float u, v;
        cube_face_uv(rx, ry, rz, face, u, v);
        int lrA = 9 - l0, lrB = 9 - l1;
        float RA = (float)(1 << lrA);
        float fxA = (u * 0.5f + 0.5f) * RA - 0.5f;
        float fyA = (v * 0.5f + 0.5f) * RA - 0.5f;
        float fxB = (l0 == l1) ? fxA : (fxA + 0.5f) * 0.5f - 0.5f;
        float fyB = (l0 == l1) ? fyA : (fyA + 0.5f) * 0.5f - 0.5f;

        float x0fA = floorf(fxA), y0fA = floorf(fyA);
        p.atx = fxA - x0fA; p.aty = fyA - y0fA;
        int WA = 1 << lrA;
        int x0A = min(max((int)x0fA, 0), WA - 1);
        int y0A = min(max((int)y0fA, 0), WA - 1);
        aI = spec_off(l0) + (face << (2 * lrA)) + (y0A << lrA) + x0A;

        float x0fB = floorf(fxB), y0fB = floorf(fyB);
        p.btx = fxB - x0fB; p.bty = fyB - y0fB;
        int WB = 1 << lrB;
        int x0B = min(max((int)x0fB, 0), WB - 1);
        int y0B = min(max((int)y0fB, 0), WB - 1);
        bI = spec_off(l1) + (face << (2 * lrB)) + (y0B << lrB) + x0B;
    }

    qA = q[aI];
    qB = q[bI];
    ql = q[lI];
    qd = q[dI];
}

__device__ __forceinline__ void finish_d(const PtS& p,
                                         uint4 qA, uint4 qB, uint4 ql, uint4 qd,
                                         float* __restrict__ o)
{
    float ar, ag, ab_, br, bg, bb;
    gather_q9(qA, p.atx, p.aty, ar, ag, ab_);
    gather_q9(qB, p.btx, p.bty, br, bg, bb);

    __half2 h00 = *reinterpret_cast<__half2*>(&ql.x);
    __half2 h01 = *reinterpret_cast<__half2*>(&ql.y);
    __half2 h10 = *reinterpret_cast<__half2*>(&ql.z);
    __half2 h11 = *reinterpret_cast<__half2*>(&ql.w);
    float2 c00 = __half22float2(h00), c01 = __half22float2(h01);
    float2 c10 = __half22float2(h10), c11 = __half22float2(h11);
    float lw00 = (1.f - p.ltx) * (1.f - p.lty);
    float lw01 = p.ltx * (1.f - p.lty);
    float lw10 = (1.f - p.ltx) * p.lty;
    float lw11 = p.ltx * p.lty;
    float fg0 = c00.x * lw00 + c01.x * lw01 + c10.x * lw10 + c11.x * lw11;
    float fg1 = c00.y * lw00 + c01.y * lw01 + c10.y * lw10 + c11.y * lw11;

    float dfr, dfg, dfb;
    gather_q9(qd, p.dtx, p.dty, dfr, dfg, dfb);
    dfr = fmaxf(dfr, 0.f); dfg = fmaxf(dfg, 0.f); dfb = fmaxf(dfb, 0.f);

    float spr = fmaxf(ar * (1.f - p.fmip) + br * p.fmip, 0.f);
    float spg = fmaxf(ag * (1.f - p.fmip) + bg * p.fmip, 0.f);
    float spb = fmaxf(ab_ * (1.f - p.fmip) + bb * p.fmip, 0.f);

    float m = p.met;
    float scx = (1.f - m) * 0.04f + p.kdx * m;
    float scy = (1.f - m) * 0.04f + p.kdy * m;
    float scz = (1.f - m) * 0.04f + p.kdz * m;
    float dcx = p.kdx * (1.f - m);
    float dcy = p.kdy * (1.f - m);
    float dcz = p.kdz * (1.f - m);

    float kds = 1.f - p.ks0;
    float om = 1.f - p.occ;
    float shx = dfr * dcx * kds + spr * (scx * fg0 + fg1) * om;
    float shy = dfg * dcy * kds + spg * (scy * fg0 + fg1) * om;
    float shz = dfb * dcz * kds + spb * (scz * fg0 + fg1) * om;

    o[0] = srgb1(fminf(fmaxf(shx, 0.f), 1.f));
    o[1] = srgb1(fminf(fmaxf(shy, 0.f), 1.f));
    o[2] = srgb1(fminf(fmaxf(shz, 0.f), 1.f));
}

// ---------------- main kernel: 2 pts/thread, zero LDS, 8 loads in flight ----
__global__ __launch_bounds__(256, 6)
void envlight_d2(const float* __restrict__ view_dir,
                 const float* __restrict__ normal,
                 const float* __restrict__ kd_p,
                 const float* __restrict__ ks_p,
                 const float* __restrict__ reflect_occ,
                 const uint4* __restrict__ q,
                 float* __restrict__ out, int n)
{
    int base = blockIdx.x << 9;
    int i0 = base + threadIdx.x;
    int i1 = i0 + 256;
    bool a0 = (i0 < n);
    bool a1 = (i1 < n);

    PtS p0, p1;
    uint4 qA0, qB0, ql0, qd0, qA1, qB1, ql1, qd1;

    if (a0) prep_d(view_dir, normal, kd_p, ks_p, reflect_occ, q, i0,
                   p0, qA0, qB0, ql0, qd0);
    if (a1) prep_d(view_dir, normal, kd_p, ks_p, reflect_occ, q, i1,
                   p1, qA1, qB1, ql1, qd1);
    if (a0) finish_d(p0, qA0, qB0, ql0, qd0, out + 3 * i0);
    if (a1) finish_d(p1, qA1, qB1, ql1, qd1, out + 3 * i1);
}

// ---------------- raw-float fallback (ws too small; shouldn't trigger) ----------------
__global__ __launch_bounds__(256)
void envlight_raw(const float* __restrict__ view_dir,
                  const float* __restrict__ normal,
                  const float* __restrict__ kd,
                  const float* __restrict__ ks,
                  const float* __restrict__ reflect_occ,
                  const float* __restrict__ diffuse_map,
                  const float* __restrict__ s0, const float* __restrict__ s1,
                  const float* __restrict__ s2, const float* __restrict__ s3,
                  const float* __restrict__ s4, const float* __restrict__ s5,
                  const float* __restrict__ fg_lut,
                  float* __restrict__ out, int n)
{
    int i = blockIdx.x * blockDim.x + threadIdx.x;
    if (i >= n) return;

    float vx = view_dir[3 * i], vy = view_dir[3 * i + 1], vz = view_dir[3 * i + 2];
    float nx = normal[3 * i],  ny = normal[3 * i + 1],  nz = normal[3 * i + 2];
    float kdx = kd[3 * i], kdy = kd[3 * i + 1], kdz = kd[3 * i + 2];
    float ks0 = ks[3 * i], rough = ks[3 * i + 1], metallic = ks[3 * i + 2];
    float occ = reflect_occ[i];

    float vdotn = vx * nx + vy * ny + vz * nz;
    float rx = 2.f * vdotn * nx - vx;
    float ry = 2.f * vdotn * ny - vy;
    float rz = 2.f * vdotn * nz - vz;
    float rinv = __builtin_amdgcn_rsqf(fmaxf(rx * rx + ry * ry + rz * rz, 1e-20f));
    rx *= rinv; ry *= rinv; rz *= rinv;

    const float* mips[6] = {s0, s1, s2, s3, s4, s5};

    const float MINR = 0.08f, MAXR = 0.5f;
    float lo = (fminf(fmaxf(rough, MINR), MAXR) - MINR) * (4.0f / (MAXR - MINR));
    float hi = (fminf(fmaxf(rough, MAXR), 1.0f) - MAXR) * (1.0f / (1.0f - MAXR)) + 4.0f;
    float lvl = fminf(fmaxf((rough < MAXR) ? lo : hi, 0.f), 5.f);
    int l0 = min(max((int)floorf(lvl), 0), 5);
    int l1 = min(l0 + 1, 5);
    float f = lvl - (float)l0;

    float acc[3][3];
    float dirs[3][3] = {{nx, ny, nz}, {rx, ry, rz}, {rx, ry, rz}};
    int lrs[3] = {4, 9 - l0, 9 - l1};
    const float* texs[3] = {diffuse_map, mips[l0], mips[l1]};
    for (int s = 0; s < 3; ++s) {
        int face; float u, v;
        cube_face_uv(dirs[s][0], dirs[s][1], dirs[s][2], face, u, v);
        int lr = lrs[s], W = 1 << lr;
        float fx = (u * 0.5f + 0.5f) * (float)W - 0.5f;
        float fy = (v * 0.5f + 0.5f) * (float)W - 0.5f;
        float x0f = floorf(fx), y0f = floorf(fy);
        float tx = fx - x0f, ty = fy - y0f;
        int x0 = min(max((int)x0f, 0), W - 1);
        int x1 = min(x0 + 1, W - 1);
        int y0 = min(max((int)y0f, 0), W - 1);
        int y1 = min(y0 + 1, W - 1);
        int base = face << (2 * lr);
        const float* t = texs[s];
        const float* p00 = t + 3 * (base + (y0 << lr) + x0);
        const float* p01 = t + 3 * (base + (y0 << lr) + x1);
        const float* p10 = t + 3 * (base + (y1 << lr) + x0);
        const float* p11 = t + 3 * (base + (y1 << lr) + x1);
        float w00 = (1.f - tx) * (1.f - ty), w01 = tx * (1.f - ty);
        float w10 = (1.f - tx) * ty, w11 = tx * ty;
        for (int c = 0; c < 3; ++c)
            acc[s][c] = p00[c] * w00 + p01[c] * w01 + p10[c] * w10 + p11[c] * w11;
    }

    float NdotV = fmaxf(vdotn, 1e-4f);
    float fx = NdotV * 256.f - 0.5f, fy = rough * 256.f - 0.5f;
    float x0f = floorf(fx), y0f = floorf(fy);
    float tx = fx - x0f, ty = fy - y0f;
    int x0 = min(max((int)x0f, 0), 255);
    int x1 = min(x0 + 1, 255);
    int y0 = min(max((int)y0f, 0), 255);
    int y1 = min(y0 + 1, 255);
    const float2* lut2 = (const float2*)fg_lut;
    float2 c00 = lut2[(y0 << 8) + x0], c01 = lut2[(y0 << 8) + x1];
    float2 c10 = lut2[(y1 << 8) + x0], c11 = lut2[(y1 << 8) + x1];
    float w00 = (1.f - tx) * (1.f - ty), w01 = tx * (1.f - ty);
    float w10 = (1.f - tx) * ty, w11 = tx * ty;
    float fg0 = c00.x * w00 + c01.x * w01 + c10.x * w10 + c11.x * w11;
    float fg1 = c00.y * w00 + c01.y * w01 + c10.y * w10 + c11.y * w11;

    float dfr = fmaxf(acc[0][0], 0.f), dfg = fmaxf(acc[0][1], 0.f), dfb = fmaxf(acc[0][2], 0.f);
    float spr = fmaxf(acc[1][0] * (1.f - f) + acc[2][0] * f, 0.f);
    float spg = fmaxf(acc[1][1] * (1.f - f) + acc[2][1] * f, 0.f);
    float spb = fmaxf(acc[1][2] * (1.f - f) + acc[2][2] * f, 0.f);

    float m = metallic;
    float scx = (1.f - m) * 0.04f + kdx * m;
    float scy = (1.f - m) * 0.04f + kdy * m;
    float scz = (1.f - m) * 0.04f + kdz * m;
    float kds = 1.f - ks0;
    float om = 1.f - occ;
    float shx = dfr * kdx * (1.f - m) * kds + spr * (scx * fg0 + fg1) * om;
    float shy = dfg * kdy * (1.f - m) * kds + spg * (scy * fg0 + fg1) * om;
    float shz = dfb * kdz * (1.f - m) * kds + spb * (scz * fg0 + fg1) * om;

    out[3 * i + 0] = srgb1(fminf(fmaxf(shx, 0.f), 1.f));
    out[3 * i + 1] = srgb1(fminf(fmaxf(shy, 0.f), 1.f));
    out[3 * i + 2] = srgb1(fminf(fmaxf(shz, 0.f), 1.f));
}

extern "C" void kernel_launch(void* const* d_in, const int* in_sizes, int n_in,
                              void* d_out, int out_size, void* d_ws, size_t ws_size,
                              hipStream_t stream) {
    const float* view_dir    = (const float*)d_in[0];
    const float* normal      = (const float*)d_in[1];
    const float* kd          = (const float*)d_in[2];
    const float* ks          = (const float*)d_in[3];
    const float* reflect_occ = (const float*)d_in[4];
    const float* diffuse_map = (const float*)d_in[5];
    const float* s0          = (const float*)d_in[6];
    const float* s1          = (const float*)d_in[7];
    const float* s2          = (const float*)d_in[8];
    const float* s3          = (const float*)d_in[9];
    const float* s4          = (const float*)d_in[10];
    const float* s5          = (const float*)d_in[11];
    const float* fg_lut      = (const float*)d_in[12];
    float* out = (float*)d_out;

    int n = in_sizes[0] / 3;
    const size_t NEED_Q = (size_t)ALL_QUADS * 16;   // ~34.6 MB

    if (ws_size >= NEED_Q) {
        uint4* q = (uint4*)d_ws;
        repack_tiled<<<N_TILES, 256, 0, stream>>>(
            s0, s1, s2, s3, s4, s5, diffuse_map, (const float2*)fg_lut, q);
        int grid = (n + 511) / 512;
        envlight_d2<<<grid, 256, 0, stream>>>(
            view_dir, normal, kd, ks, reflect_occ, q, out, n);
    } else {
        int grid = (n + 255) / 256;
        envlight_raw<<<grid, 256, 0, stream>>>(
            view_dir, normal, kd, ks, reflect_occ, diffuse_map,
            s0, s1, s2, s3, s4, s5, fg_lut, out, n);
    }
}

// Round 8
// 233.431 us; speedup vs baseline: 1.1860x; 1.1860x over previous
//
#include <hip/hip_runtime.h>
#include <hip/hip_fp16.h>
#include <math.h>

// EnvironmentLight IBL shade, R16.
// R15 post-mortem: 134us, WRITE 170MB scratch at only 40/84 VGPR -> NOT
// register pressure. Divergent-guarded struct/ref out-params (PtS&, uint4&)
// defeated SROA -> aggregates allocated in LOCAL MEMORY (rule-#20 family).
// R11/R12/R15 all show the same 40-VGPR+scratch signature; flat R14 = 28 VGPR,
// zero scratch. The 2-pt schedule was never actually tested.
// R16: FLAT 2-pt. Hand-inlined suffixed scalars, no structs, no ref out-args,
// and ZERO divergent guards (host dispatches this kernel only when n%512==0;
// n=2097152=512*4096). prep0 -> prep1 -> finish0 -> finish1; 8 scattered
// dwordx4 in flight per wave. launch_bounds(256,6): 84-VGPR budget, est ~70.
// Diagnostic: WRITE_SIZE must be exactly 24576 KB; VGPR 60-84.

typedef unsigned int u32;

// ---------------- RGB9E5 ----------------
__device__ __forceinline__ u32 enc9e5(float r, float g, float b) {
    r = fminf(fmaxf(r, 0.f), 65408.f);
    g = fminf(fmaxf(g, 0.f), 65408.f);
    b = fminf(fmaxf(b, 0.f), 65408.f);
    float maxc = fmaxf(r, fmaxf(g, b));
    int e = ((__float_as_int(maxc) >> 23) & 0xff) - 127;
    int exp_p = max(e + 16, 0);
    float rd = __int_as_float((151 - exp_p) << 23);   // 2^(24-exp_p), exact
    int maxm = (int)(maxc * rd + 0.5f);
    if (maxm == 512) { exp_p += 1; rd *= 0.5f; }
    u32 rm = (u32)(r * rd + 0.5f);
    u32 gm = (u32)(g * rd + 0.5f);
    u32 bm = (u32)(b * rd + 0.5f);
    return rm | (gm << 9) | (bm << 18) | ((u32)exp_p << 27);
}

__device__ __forceinline__ void dec9e5_acc(u32 pk, float w, float& r, float& g, float& b) {
    float scale = __int_as_float((int)(((pk >> 27) & 31u) + 103u) << 23) * w;
    r += (float)(pk & 511u) * scale;
    g += (float)((pk >> 9) & 511u) * scale;
    b += (float)((pk >> 18) & 511u) * scale;
}

__device__ __forceinline__ void gather_q9(uint4 q, float tx, float ty,
                                          float& r, float& g, float& b) {
    float w00 = (1.f - tx) * (1.f - ty);
    float w01 = tx * (1.f - ty);
    float w10 = (1.f - tx) * ty;
    float w11 = tx * ty;
    r = 0.f; g = 0.f; b = 0.f;
    dec9e5_acc(q.x, w00, r, g, b);
    dec9e5_acc(q.y, w01, r, g, b);
    dec9e5_acc(q.z, w10, r, g, b);
    dec9e5_acc(q.w, w11, r, g, b);
}

__device__ __forceinline__ float srgb1(float x) {
    float p = 1.055f * __builtin_amdgcn_exp2f(
                  __builtin_amdgcn_logf(fmaxf(x, 0.0031308f)) * (1.0f / 2.4f)) - 0.055f;
    return (x <= 0.0031308f) ? (12.92f * x) : p;
}

__device__ __forceinline__ void cube_face_uv(float dx, float dy, float dz,
                                             int& face, float& u, float& v) {
    float ax = fabsf(dx), ay = fabsf(dy), az = fabsf(dz);
    bool is_x = (ax >= ay) && (ax >= az);
    bool is_y = (!is_x) && (ay >= az);
    face = is_x ? (dx > 0.f ? 0 : 1)
                : (is_y ? (dy > 0.f ? 2 : 3) : (dz > 0.f ? 4 : 5));
    float ma = fmaxf(is_x ? ax : (is_y ? ay : az), 1e-20f);
    float uu = is_x ? (dx > 0.f ? -dz : dz) : (is_y ? dx : (dz > 0.f ? dx : -dx));
    float vv = is_y ? (dy > 0.f ? dz : -dz) : -dy;
    float inv = __builtin_amdgcn_rcpf(ma);
    u = uu * inv;
    v = vv * inv;
}

// ---------------- layout constants ----------------
#define SPEC_TOTAL 2096640
#define DIF_OFF    SPEC_TOTAL
#define LUT_OFF    (SPEC_TOTAL + 1536)
#define ALL_QUADS  (SPEC_TOTAL + 1536 + 65536)
#define N_TILES    8452   // 8190 spec + 6 dif + 256 lut

// OFF(l) = 2^21 - (2^21 >> 2l): 0,1572864,1966080,2064384,2088960,2095104
__device__ __forceinline__ int spec_off(int l) {
    return (1 << 21) - ((1 << 21) >> (2 * l));
}

// ---------------- tiled repack (unchanged from R11, verified) ----------------
__global__ __launch_bounds__(256)
void repack_tiled(const float* __restrict__ s0, const float* __restrict__ s1,
                  const float* __restrict__ s2, const float* __restrict__ s3,
                  const float* __restrict__ s4, const float* __restrict__ s5,
                  const float* __restrict__ diffuse_map,
                  const float2* __restrict__ lut,
                  uint4* __restrict__ dst)
{
    __shared__ u32 L[289];
    int b = blockIdx.x;
    int tid = threadIdx.x;

    if (b >= 8196) {
        int t = b - 8196;
        int ty0 = (t >> 4) << 4;
        int tx0 = (t & 15) << 4;
        for (int e = tid; e < 289; e += 256) {
            int ey = e / 17, ex = e - ey * 17;
            int gy = min(ty0 + ey, 255), gx = min(tx0 + ex, 255);
            float2 c = lut[(gy << 8) + gx];
            __half2 h = __floats2half2_rn(c.x, c.y);
            L[e] = *reinterpret_cast<u32*>(&h);
        }
        __syncthreads();
        int qx = tid & 15, qy = tid >> 4;
        uint4 qv;
        qv.x = L[qy * 17 + qx];       qv.y = L[qy * 17 + qx + 1];
        qv.z = L[(qy + 1) * 17 + qx]; qv.w = L[(qy + 1) * 17 + qx + 1];
        dst[LUT_OFF + ((ty0 + qy) << 8) + tx0 + qx] = qv;
        return;
    }

    const float* src; int lr, tbase, doff;
    if      (b < 6144) { src = s0; lr = 9; tbase = 0;    doff = 0; }
    else if (b < 7680) { src = s1; lr = 8; tbase = 6144; doff = 1572864; }
    else if (b < 8064) { src = s2; lr = 7; tbase = 7680; doff = 1966080; }
    else if (b < 8160) { src = s3; lr = 6; tbase = 8064; doff = 2064384; }
    else if (b < 8184) { src = s4; lr = 5; tbase = 8160; doff = 2088960; }
    else if (b < 8190) { src = s5; lr = 4; tbase = 8184; doff = 2095104; }
    else               { src = diffuse_map; lr = 4; tbase = 8190; doff = DIF_OFF; }

    int W = 1 << lr;
    int lt = lr - 4;
    int local = b - tbase;
    int face = local >> (2 * lt);
    int rem  = local & ((1 << (2 * lt)) - 1);
    int ty0 = (rem >> lt) << 4;
    int tx0 = (rem & ((1 << lt) - 1)) << 4;
    int fbase = face << (2 * lr);

    for (int e = tid; e < 289; e += 256) {
        int ey = e / 17, ex = e - ey * 17;
        int gy = min(ty0 + ey, W - 1), gx = min(tx0 + ex, W - 1);
        int idx = 3 * (fbase + (gy << lr) + gx);
        L[e] = enc9e5(src[idx], src[idx + 1], src[idx + 2]);
    }
    __syncthreads();
    int qx = tid & 15, qy = tid >> 4;
    uint4 qv;
    qv.x = L[qy * 17 + qx];       qv.y = L[qy * 17 + qx + 1];
    qv.z = L[(qy + 1) * 17 + qx]; qv.w = L[(qy + 1) * 17 + qx + 1];
    dst[doff + fbase + ((ty0 + qy) << lr) + tx0 + qx] = qv;
}

// Address-computation macro: from (vx..vz, nx..nz, rough, vdotn) suffixed by S,
// produces dtx/dty/ltx/lty/atx/aty/btx/bty/fmip/aI/bI/lI/dI suffixed by S.
// Pure textual flattening -- no structs, no refs, everything scalar.
#define PREP_ADDR(S)                                                            \
    float vdotn##S = vx##S * nx##S + vy##S * ny##S + vz##S * nz##S;             \
    float rx##S = 2.f * vdotn##S * nx##S - vx##S;                               \
    float ry##S = 2.f * vdotn##S * ny##S - vy##S;                               \
    float rz##S = 2.f * vdotn##S * nz##S - vz##S;                               \
    {                                                                           \
        float rinv = __builtin_amdgcn_rsqf(                                     \
            fmaxf(rx##S * rx##S + ry##S * ry##S + rz##S * rz##S, 1e-20f));      \
        rx##S *= rinv; ry##S *= rinv; rz##S *= rinv;                            \
    }                                                                           \
    float dtx##S, dty##S; int dI##S;                                            \
    {                                                                           \
        int face; float u, v;                                                   \
        cube_face_uv(nx##S, ny##S, nz##S, face, u, v);                          \
        float fx = (u * 0.5f + 0.5f) * 16.f - 0.5f;                             \
        float fy = (v * 0.5f + 0.5f) * 16.f - 0.5f;                             \
        float x0f = floorf(fx), y0f = floorf(fy);                               \
        dtx##S = fx - x0f; dty##S = fy - y0f;                                   \
        int x0 = min(max((int)x0f, 0), 15);                                     \
        int y0 = min(max((int)y0f, 0), 15);                                     \
        dI##S = DIF_OFF + (face << 8) + (y0 << 4) + x0;                         \
    }                                                                           \
    float ltx##S, lty##S; int lI##S;                                            \
    {                                                                           \
        float NdotV = fmaxf(vdotn##S, 1e-4f);                                   \
        float fx = NdotV * 256.f - 0.5f;                                        \
        float fy = rough##S * 256.f - 0.5f;                                     \
        float x0f = floorf(fx), y0f = floorf(fy);                               \
        ltx##S = fx - x0f; lty##S = fy - y0f;                                   \
        int x0 = min(max((int)x0f, 0), 255);                                    \
        int y0 = min(max((int)y0f, 0), 255);                                    \
        lI##S = LUT_OFF + (y0 << 8) + x0;                                       \
    }                                                                           \
    float fmip##S;                                                              \
    float atx##S, aty##S, btx##S, bty##S; int aI##S, bI##S;                     \
    {                                                                           \
        const float MINR = 0.08f, MAXR = 0.5f;                                  \
        float lo = (fminf(fmaxf(rough##S, MINR), MAXR) - MINR)                  \
                   * (4.0f / (MAXR - MINR));                                    \
        float hi = (fminf(fmaxf(rough##S, MAXR), 1.0f) - MAXR)                  \
                   * (1.0f / (1.0f - MAXR)) + 4.0f;                             \
        float lvl = fminf(fmaxf((rough##S < MAXR) ? lo : hi, 0.f), 5.f);        \
        int l0 = min(max((int)floorf(lvl), 0), 5);                              \
        int l1 = min(l0 + 1, 5);                                                \
        fmip##S = lvl - (float)l0;                                              \
        int face; float u, v;                                                   \
        cube_face_uv(rx##S, ry##S, rz##S, face, u, v);                          \
        int lrA = 9 - l0, lrB = 9 - l1;                                         \
        float RA = (float)(1 << lrA);                                           \
        float fxA = (u * 0.5f + 0.5f) * RA - 0.5f;                              \
        float fyA = (v * 0.5f + 0.5f) * RA - 0.5f;                              \
        float fxB = (l0 == l1) ? fxA : (fxA + 0.5f) * 0.5f - 0.5f;              \
        float fyB = (l0 == l1) ? fyA : (fyA + 0.5f) * 0.5f - 0.5f;              \
        float x0fA = floorf(fxA), y0fA = floorf(fyA);                           \
        atx##S = fxA - x0fA; aty##S = fyA - y0fA;                               \
        int WA = 1 << lrA;                                                      \
        int x0A = min(max((int)x0fA, 0), WA - 1);                               \
        int y0A = min(max((int)y0fA, 0), WA - 1);                               \
        aI##S = spec_off(l0) + (face << (2 * lrA)) + (y0A << lrA) + x0A;        \
        float x0fB = floorf(fxB), y0fB = floorf(fyB);                           \
        btx##S = fxB - x0fB; bty##S = fyB - y0fB;                               \
        int WB = 1 << lrB;                                                      \
        int x0B = min(max((int)x0fB, 0), WB - 1);                               \
        int y0B = min(max((int)y0fB, 0), WB - 1);                               \
        bI##S = spec_off(l1) + (face << (2 * lrB)) + (y0B << lrB) + x0B;        \
    }

// Finish macro: consumes quads + fracs + finish inputs for suffix S,
// writes 3 floats to out + 3*i.
#define FINISH(S, i)                                                            \
    {                                                                           \
        float ar, ag, ab_, br_, bg_, bb_;                                       \
        gather_q9(qA##S, atx##S, aty##S, ar, ag, ab_);                          \
        gather_q9(qB##S, btx##S, bty##S, br_, bg_, bb_);                        \
        __half2 h00 = *reinterpret_cast<__half2*>(&ql##S.x);                    \
        __half2 h01 = *reinterpret_cast<__half2*>(&ql##S.y);                    \
        __half2 h10 = *reinterpret_cast<__half2*>(&ql##S.z);                    \
        __half2 h11 = *reinterpret_cast<__half2*>(&ql##S.w);                    \
        float2 c00 = __half22float2(h00), c01 = __half22float2(h01);            \
        float2 c10 = __half22float2(h10), c11 = __half22float2(h11);            \
        float lw00 = (1.f - ltx##S) * (1.f - lty##S);                           \
        float lw01 = ltx##S * (1.f - lty##S);                                   \
        float lw10 = (1.f - ltx##S) * lty##S;                                   \
        float lw11 = ltx##S * lty##S;                                           \
        float fg0 = c00.x * lw00 + c01.x * lw01 + c10.x * lw10 + c11.x * lw11;  \
        float fg1 = c00.y * lw00 + c01.y * lw01 + c10.y * lw10 + c11.y * lw11;  \
        float dfr, dfg, dfb;                                                    \
        gather_q9(qd##S, dtx##S, dty##S, dfr, dfg, dfb);                        \
        dfr = fmaxf(dfr, 0.f); dfg = fmaxf(dfg, 0.f); dfb = fmaxf(dfb, 0.f);    \
        float spr = fmaxf(ar * (1.f - fmip##S) + br_ * fmip##S, 0.f);           \
        float spg = fmaxf(ag * (1.f - fmip##S) + bg_ * fmip##S, 0.f);           \
        float spb = fmaxf(ab_ * (1.f - fmip##S) + bb_ * fmip##S, 0.f);          \
        float m = met##S;                                                       \
        float scx = (1.f - m) * 0.04f + kdx##S * m;                             \
        float scy = (1.f - m) * 0.04f + kdy##S * m;                             \
        float scz = (1.f - m) * 0.04f + kdz##S * m;                             \
        float dcx = kdx##S * (1.f - m);                                         \
        float dcy = kdy##S * (1.f - m);                                         \
        float dcz = kdz##S * (1.f - m);                                         \
        float kds = 1.f - ks0##S;                                               \
        float om = 1.f - occ##S;                                                \
        float shx = dfr * dcx * kds + spr * (scx * fg0 + fg1) * om;             \
        float shy = dfg * dcy * kds + spg * (scy * fg0 + fg1) * om;             \
        float shz = dfb * dcz * kds + spb * (scz * fg0 + fg1) * om;             \
        out[3 * (i) + 0] = srgb1(fminf(fmaxf(shx, 0.f), 1.f));                  \
        out[3 * (i) + 1] = srgb1(fminf(fmaxf(shy, 0.f), 1.f));                  \
        out[3 * (i) + 2] = srgb1(fminf(fmaxf(shz, 0.f), 1.f));                  \
    }

// ---------------- main kernel: flat 2 pts/thread, zero LDS, no guards -------
// Host guarantees n % 512 == 0 for this kernel.
__global__ __launch_bounds__(256, 6)
void envlight_d2f(const float* __restrict__ view_dir,
                  const float* __restrict__ normal,
                  const float* __restrict__ kd_p,
                  const float* __restrict__ ks_p,
                  const float* __restrict__ reflect_occ,
                  const uint4* __restrict__ q,
                  float* __restrict__ out)
{
    int i0 = (blockIdx.x << 9) + threadIdx.x;
    int i1 = i0 + 256;

    // ---- pt0: inputs + addresses + issue 4 scattered loads ----
    float3 v30 = ((const float3*)view_dir)[i0];
    float3 n30 = ((const float3*)normal)[i0];
    float3 k30 = ((const float3*)kd_p)[i0];
    float3 s30 = ((const float3*)ks_p)[i0];
    float occ0 = reflect_occ[i0];
    float vx0 = v30.x, vy0 = v30.y, vz0 = v30.z;
    float nx0 = n30.x, ny0 = n30.y, nz0 = n30.z;
    float kdx0 = k30.x, kdy0 = k30.y, kdz0 = k30.z;
    float ks00 = s30.x, rough0 = s30.y, met0 = s30.z;
    PREP_ADDR(0)
    uint4 qA0 = q[aI0];
    uint4 qB0 = q[bI0];
    uint4 ql0 = q[lI0];
    uint4 qd0 = q[dI0];

    // ---- pt1: inputs + addresses + issue 4 scattered loads ----
    float3 v31 = ((const float3*)view_dir)[i1];
    float3 n31 = ((const float3*)normal)[i1];
    float3 k31 = ((const float3*)kd_p)[i1];
    float3 s31 = ((const float3*)ks_p)[i1];
    float occ1 = reflect_occ[i1];
    float vx1 = v31.x, vy1 = v31.y, vz1 = v31.z;
    float nx1 = n31.x, ny1 = n31.y, nz1 = n31.z;
    float kdx1 = k31.x, kdy1 = k31.y, kdz1 = k31.z;
    float ks01 = s31.x, rough1 = s31.y, met1 = s31.z;
    PREP_ADDR(1)
    uint4 qA1 = q[aI1];
    uint4 qB1 = q[bI1];
    uint4 ql1 = q[lI1];
    uint4 qd1 = q[dI1];

    // ---- finish both ----
    FINISH(0, i0)
    FINISH(1, i1)
}

// ---------------- 1-pt direct kernel (R14, for n % 512 != 0) ----------------
__global__ __launch_bounds__(256, 8)
void envlight_direct(const float* __restrict__ view_dir,
                     const float* __restrict__ normal,
                     const float* __restrict__ kd_p,
                     const float* __restrict__ ks_p,
                     const float* __restrict__ reflect_occ,
                     const uint4* __restrict__ q,
                     float* __restrict__ out, int n)
{
    int i0 = blockIdx.x * blockDim.x + threadIdx.x;
    if (i0 >= n) return;

    float3 v30 = ((const float3*)view_dir)[i0];
    float3 n30 = ((const float3*)normal)[i0];
    float3 k30 = ((const float3*)kd_p)[i0];
    float3 s30 = ((const float3*)ks_p)[i0];
    float occ0 = reflect_occ[i0];
    float vx0 = v30.x, vy0 = v30.y, vz0 = v30.z;
    float nx0 = n30.x, ny0 = n30.y, nz0 = n30.z;
    float kdx0 = k30.x, kdy0 = k30.y, kdz0 = k30.z;
    float ks00 = s30.x, rough0 = s30.y, met0 = s30.z;
    PREP_ADDR(0)
    uint4 qA0 = q[aI0];
    uint4 qB0 = q[bI0];
    uint4 ql0 = q[lI0];
    uint4 qd0 = q[dI0];
    FINISH(0, i0)
}

// ---------------- raw-float fallback (ws too small; shouldn't trigger) ----------------
__global__ __launch_bounds__(256)
void envlight_raw(const float* __restrict__ view_dir,
                  const float* __restrict__ normal,
                  const float* __restrict__ kd,
                  const float* __restrict__ ks,
                  const float* __restrict__ reflect_occ,
                  const float* __restrict__ diffuse_map,
                  const float* __restrict__ s0, const float* __restrict__ s1,
                  const float* __restrict__ s2, const float* __restrict__ s3,
                  const float* __restrict__ s4, const float* __restrict__ s5,
                  const float* __restrict__ fg_lut,
                  float* __restrict__ out, int n)
{
    int i = blockIdx.x * blockDim.x + threadIdx.x;
    if (i >= n) return;

    float vx = view_dir[3 * i], vy = view_dir[3 * i + 1], vz = view_dir[3 * i + 2];
    float nx = normal[3 * i],  ny = normal[3 * i + 1],  nz = normal[3 * i + 2];
    float kdx = kd[3 * i], kdy = kd[3 * i + 1], kdz = kd[3 * i + 2];
    float ks0 = ks[3 * i], rough = ks[3 * i + 1], metallic = ks[3 * i + 2];
    float occ = reflect_occ[i];

    float vdotn = vx * nx + vy * ny + vz * nz;
    float rx = 2.f * vdotn * nx - vx;
    float ry = 2.f * vdotn * ny - vy;
    float rz = 2.f * vdotn * nz - vz;
    float rinv = __builtin_amdgcn_rsqf(fmaxf(rx * rx + ry * ry + rz * rz, 1e-20f));
    rx *= rinv; ry *= rinv; rz *= rinv;

    const float* mips[6] = {s0, s1, s2, s3, s4, s5};

    const float MINR = 0.08f, MAXR = 0.5f;
    float lo = (fminf(fmaxf(rough, MINR), MAXR) - MINR) * (4.0f / (MAXR - MINR));
    float hi = (fminf(fmaxf(rough, MAXR), 1.0f) - MAXR) * (1.0f / (1.0f - MAXR)) + 4.0f;
    float lvl = fminf(fmaxf((rough < MAXR) ? lo : hi, 0.f), 5.f);
    int l0 = min(max((int)floorf(lvl), 0), 5);
    int l1 = min(l0 + 1, 5);
    float f = lvl - (float)l0;

    float acc[3][3];
    float dirs[3][3] = {{nx, ny, nz}, {rx, ry, rz}, {rx, ry, rz}};
    int lrs[3] = {4, 9 - l0, 9 - l1};
    const float* texs[3] = {diffuse_map, mips[l0], mips[l1]};
    for (int s = 0; s < 3; ++s) {
        int face; float u, v;
        cube_face_uv(dirs[s][0], dirs[s][1], dirs[s][2], face, u, v);
        int lr = lrs[s], W = 1 << lr;
        float fx = (u * 0.5f + 0.5f) * (float)W - 0.5f;
        float fy = (v * 0.5f + 0.5f) * (float)W - 0.5f;
        float x0f = floorf(fx), y0f = floorf(fy);
        float tx = fx - x0f, ty = fy - y0f;
        int x0 = min(max((int)x0f, 0), W - 1);
        int x1 = min(x0 + 1, W - 1);
        int y0 = min(max((int)y0f, 0), W - 1);
        int y1 = min(y0 + 1, W - 1);
        int base = face << (2 * lr);
        const float* t = texs[s];
        const float* p00 = t + 3 * (base + (y0 << lr) + x0);
        const float* p01 = t + 3 * (base + (y0 << lr) + x1);
        const float* p10 = t + 3 * (base + (y1 << lr) + x0);
        const float* p11 = t + 3 * (base + (y1 << lr) + x1);
        float w00 = (1.f - tx) * (1.f - ty), w01 = tx * (1.f - ty);
        float w10 = (1.f - tx) * ty, w11 = tx * ty;
        for (int c = 0; c < 3; ++c)
            acc[s][c] = p00[c] * w00 + p01[c] * w01 + p10[c] * w10 + p11[c] * w11;
    }

    float NdotV = fmaxf(vdotn, 1e-4f);
    float fx = NdotV * 256.f - 0.5f, fy = rough * 256.f - 0.5f;
    float x0f = floorf(fx), y0f = floorf(fy);
    float tx = fx - x0f, ty = fy - y0f;
    int x0 = min(max((int)x0f, 0), 255);
    int x1 = min(x0 + 1, 255);
    int y0 = min(max((int)y0f, 0), 255);
    int y1 = min(y0 + 1, 255);
    const float2* lut2 = (const float2*)fg_lut;
    float2 c00 = lut2[(y0 << 8) + x0], c01 = lut2[(y0 << 8) + x1];
    float2 c10 = lut2[(y1 << 8) + x0], c11 = lut2[(y1 << 8) + x1];
    float w00 = (1.f - tx) * (1.f - ty), w01 = tx * (1.f - ty);
    float w10 = (1.f - tx) * ty, w11 = tx * ty;
    float fg0 = c00.x * w00 + c01.x * w01 + c10.x * w10 + c11.x * w11;
    float fg1 = c00.y * w00 + c01.y * w01 + c10.y * w10 + c11.y * w11;

    float dfr = fmaxf(acc[0][0], 0.f), dfg = fmaxf(acc[0][1], 0.f), dfb = fmaxf(acc[0][2], 0.f);
    float spr = fmaxf(acc[1][0] * (1.f - f) + acc[2][0] * f, 0.f);
    float spg = fmaxf(acc[1][1] * (1.f - f) + acc[2][1] * f, 0.f);
    float spb = fmaxf(acc[1][2] * (1.f - f) + acc[2][2] * f, 0.f);

    float m = metallic;
    float scx = (1.f - m) * 0.04f + kdx * m;
    float scy = (1.f - m) * 0.04f + kdy * m;
    float scz = (1.f - m) * 0.04f + kdz * m;
    float kds = 1.f - ks0;
    float om = 1.f - occ;
    float shx = dfr * kdx * (1.f - m) * kds + spr * (scx * fg0 + fg1) * om;
    float shy = dfg * kdy * (1.f - m) * kds + spg * (scy * fg0 + fg1) * om;
    float shz = dfb * kdz * (1.f - m) * kds + spb * (scz * fg0 + fg1) * om;

    out[3 * i + 0] = srgb1(fminf(fmaxf(shx, 0.f), 1.f));
    out[3 * i + 1] = srgb1(fminf(fmaxf(shy, 0.f), 1.f));
    out[3 * i + 2] = srgb1(fminf(fmaxf(shz, 0.f), 1.f));
}

extern "C" void kernel_launch(void* const* d_in, const int* in_sizes, int n_in,
                              void* d_out, int out_size, void* d_ws, size_t ws_size,
                              hipStream_t stream) {
    const float* view_dir    = (const float*)d_in[0];
    const float* normal      = (const float*)d_in[1];
    const float* kd          = (const float*)d_in[2];
    const float* ks          = (const float*)d_in[3];
    const float* reflect_occ = (const float*)d_in[4];
    const float* diffuse_map = (const float*)d_in[5];
    const float* s0          = (const float*)d_in[6];
    const float* s1          = (const float*)d_in[7];
    const float* s2          = (const float*)d_in[8];
    const float* s3          = (const float*)d_in[9];
    const float* s4          = (const float*)d_in[10];
    const float* s5          = (const float*)d_in[11];
    const float* fg_lut      = (const float*)d_in[12];
    float* out = (float*)d_out;

    int n = in_sizes[0] / 3;
    const size_t NEED_Q = (size_t)ALL_QUADS * 16;   // ~34.6 MB

    if (ws_size >= NEED_Q) {
        uint4* q = (uint4*)d_ws;
        repack_tiled<<<N_TILES, 256, 0, stream>>>(
            s0, s1, s2, s3, s4, s5, diffuse_map, (const float2*)fg_lut, q);
        if ((n & 511) == 0) {
            envlight_d2f<<<n >> 9, 256, 0, stream>>>(
                view_dir, normal, kd, ks, reflect_occ, q, out);
        } else {
            int grid = (n + 255) / 256;
            envlight_direct<<<grid, 256, 0, stream>>>(
                view_dir, normal, kd, ks, reflect_occ, q, out, n);
        }
    } else {
        int grid = (n + 255) / 256;
        envlight_raw<<<grid, 256, 0, stream>>>(
            view_dir, normal, kd, ks, reflect_occ, diffuse_map,
            s0, s1, s2, s3, s4, s5, fg_lut, out, n);
    }
}